// Round 11
// baseline (288.879 us; speedup 1.0000x reference)
//
#include <hip/hip_runtime.h>
#include <cstdint>
#include <cstddef>

typedef unsigned short u16;
typedef __attribute__((ext_vector_type(8))) short short8;    // 8 bf16 (4 VGPRs) MFMA A/B frag (x32)
typedef __attribute__((ext_vector_type(4))) short short4v;   // 4 bf16 (2 VGPRs) MFMA A/B frag (x16)
typedef __attribute__((ext_vector_type(4))) float float4v;   // MFMA C/D frag
typedef __attribute__((ext_vector_type(4))) unsigned short ushort4v;
typedef __attribute__((ext_vector_type(2))) float float2v;

// ---------- helpers ----------
__device__ __forceinline__ u16 f2bf(float f) {
    union { float f; uint32_t u; } x; x.f = f;
    uint32_t r = x.u + 0x7fffu + ((x.u >> 16) & 1u);   // RTNE
    return (u16)(r >> 16);
}
// pack two fp32 -> two bf16 in one dword
__device__ __forceinline__ uint32_t pack_bf16x2(float lo, float hi) {
    union { float f; uint32_t u; } a, b; a.f = lo; b.f = hi;
    return __builtin_amdgcn_perm(b.u + 0x8000u, a.u + 0x8000u, 0x07060302u);
}
// async global->LDS, 16B per lane (HW: wave-uniform base + lane*16)
__device__ __forceinline__ void gl_lds16(const u16* g, u16* l) {
    __builtin_amdgcn_global_load_lds(
        (const __attribute__((address_space(1))) void*)g,
        (__attribute__((address_space(3))) void*)l, 16, 0, 0);
}

// ---------- 1. merged prep: cast x, rope table, weight transposes ----------
__global__ __launch_bounds__(256) void prep(const float4v* __restrict__ x,
                                            const float* __restrict__ Wq,
                                            const float* __restrict__ Wk,
                                            const float* __restrict__ Wv,
                                            const float* __restrict__ Wo,
                                            ushort4v* __restrict__ xb,
                                            u16* __restrict__ wqkv_t,
                                            u16* __restrict__ wo_t,
                                            float2v* __restrict__ tab) {
    __shared__ float lds[64][33];
    const int bid = blockIdx.x;
    const int tid = threadIdx.x;
    if (bid < 8192) {
        const int i = bid * 256 + tid;
        float4v v = x[i];
        ushort4v o;
        #pragma unroll
        for (int j = 0; j < 4; ++j) o[j] = f2bf(v[j]);
        xb[i] = o;
        return;
    }
    if (bid < 8448) {
        const int idx = (bid - 8192) * 256 + tid;   // 65536
        const int t = idx >> 5;
        const int i = idx & 31;
        const float invf = exp2f(-(float)i * (19.931568569324174f / 32.0f));
        float sv, cv;
        sincosf((float)t * invf, &sv, &cv);
        float2v o; o[0] = cv; o[1] = sv;
        tab[idx] = o;
        return;
    }
    const float* src;
    int Ns, n0, k0, scol0;
    u16* dst;
    if (bid < 11520) {                       // 3072 wqkv blocks (96 n x 32 k64)
        const int id = bid - 8448;
        const int bx = id % 96, by = id / 96;
        n0 = bx * 32; k0 = by * 64;
        if (n0 < 2048)      { src = Wq; Ns = 2048; scol0 = n0; }
        else if (n0 < 2560) { src = Wk; Ns = 512;  scol0 = n0 - 2048; }
        else                { src = Wv; Ns = 512;  scol0 = n0 - 2560; }
        dst = wqkv_t;
    } else {                                 // 2048 wo blocks (64 n x 32 k64)
        const int id = bid - 11520;
        const int bx = id & 63, by = id >> 6;
        n0 = bx * 32; k0 = by * 64;
        src = Wo; Ns = 2048; scol0 = n0;
        dst = wo_t;
    }
    const int row64 = tid >> 2;              // k local, 0..63
    const int c8    = (tid & 3) * 8;         // n local, 0,8,16,24
    const float* sp = src + (size_t)(k0 + row64) * Ns + scol0 + c8;
    const float4v va = *(const float4v*)sp;
    const float4v vb = *(const float4v*)(sp + 4);
    #pragma unroll
    for (int i = 0; i < 4; ++i) { lds[row64][c8 + i] = va[i]; lds[row64][c8 + 4 + i] = vb[i]; }
    __syncthreads();
    const int nrow = tid >> 3;               // n local, 0..31
    const int kk   = (tid & 7) * 8;          // k local, 0..56
    short8 o8;
    #pragma unroll
    for (int i = 0; i < 8; ++i) o8[i] = (short)f2bf(lds[kk + i][nrow]);
    *(short8*)(dst + (size_t)(n0 + nrow) * 2048 + k0 + kk) = o8;
}

// ======== 4-deep ring-buffer GEMM main loop (T3/T4-style counted vmcnt) ========
// Tile 256m x 128n, BK=32, 512 thr = 8 waves (4m x 2n), 64x64 per wave.
// LDS ring: 4 buffers x (A 256x32 + B 128x32) bf16 = 4 x 24KB = 96 KB.
// Step it: compute from buf[it&3], stage buf[(it+3)&3] -> issue-to-use = 3
// steps (~1000cy > HBM latency). Publish wait is counted vmcnt(6) (2-step-old
// loads, nearly free) + RAW s_barrier -- never the __syncthreads vmcnt(0)
// drain that capped the m97 structure at 768 TF here.
// Chunk-XOR (col4 ^= row&3) baked into staging SOURCE addr; frag ds_read_b128
// applies the same XOR -> conflict-free reads (session-verified in attn).
#define GEMM_RING_PROLOG(Aptr, Bptr, KK)                                       \
    __shared__ u16 lds[4 * 12288];                                             \
    const int tid  = threadIdx.x;                                              \
    const int wave = tid >> 6;                                                 \
    const int lane = tid & 63;                                                 \
    const int quad = lane >> 4;                                                \
    const int l15  = lane & 15;                                                \
    const long m0 = (long)blockIdx.x * 256;                                    \
    const long n0 = (long)blockIdx.y * 128;                                    \
    const int wm = (wave >> 1) * 64;                                           \
    const int wn = (wave & 1) * 64;                                            \
    const int srow = tid >> 2;                                                 \
    const int sgc  = (((tid & 3) ^ (srow & 3)) << 3);                          \
    const u16* gA0 = (Aptr) + (m0 + srow) * (long)(KK) + sgc;                  \
    const u16* gA1 = (Aptr) + (m0 + srow + 128) * (long)(KK) + sgc;            \
    const u16* gB0 = (Bptr) + (n0 + srow) * (long)(KK) + sgc;                  \
    const int dA0 = tid * 8, dA1 = tid * 8 + 4096, dB = 8192 + tid * 8;        \
    const int sa   = ((quad ^ (l15 & 3)) << 3);                                \
    const int aoff = (wm + l15) * 32 + sa;                                     \
    const int boff = 8192 + (wn + l15) * 32 + sa;                              \
    float4v acc[4][4];                                                         \
    _Pragma("unroll")                                                          \
    for (int i = 0; i < 4; ++i)                                                \
        _Pragma("unroll")                                                      \
        for (int j = 0; j < 4; ++j)                                            \
            _Pragma("unroll")                                                  \
            for (int r = 0; r < 4; ++r) acc[i][j][r] = 0.0f;                   \
    auto stg = [&](int s) {                                                    \
        u16* Ld = lds + (s & 3) * 12288;                                       \
        const long k0 = (long)s << 5;                                          \
        gl_lds16(gA0 + k0, Ld + dA0);                                          \
        gl_lds16(gA1 + k0, Ld + dA1);                                          \
        gl_lds16(gB0 + k0, Ld + dB);                                           \
    };                                                                         \
    auto cmp = [&](int it) {                                                   \
        const u16* Lp = lds + (it & 3) * 12288;                                \
        short8 af[4], bf[4];                                                   \
        _Pragma("unroll")                                                      \
        for (int mt = 0; mt < 4; ++mt)                                         \
            af[mt] = *(const short8*)(Lp + aoff + mt * 512);                   \
        _Pragma("unroll")                                                      \
        for (int nt = 0; nt < 4; ++nt)                                         \
            bf[nt] = *(const short8*)(Lp + boff + nt * 512);                   \
        __builtin_amdgcn_s_setprio(1);                                         \
        _Pragma("unroll")                                                      \
        for (int mt = 0; mt < 4; ++mt)                                         \
            _Pragma("unroll")                                                  \
            for (int nt = 0; nt < 4; ++nt)                                     \
                acc[mt][nt] = __builtin_amdgcn_mfma_f32_16x16x32_bf16(         \
                    af[mt], bf[nt], acc[mt][nt], 0, 0, 0);                     \
        __builtin_amdgcn_s_setprio(0);                                         \
    };                                                                         \
    stg(0); stg(1); stg(2);                                                    \
    asm volatile("s_waitcnt vmcnt(6)" ::: "memory");                           \
    __builtin_amdgcn_s_barrier();                                              \
    asm volatile("" ::: "memory");                                             \
    const int n_k = (KK) >> 5;                                                 \
    for (int it = 0; it < n_k - 3; ++it) {                                     \
        stg(it + 3);                                                           \
        cmp(it);                                                               \
        asm volatile("s_waitcnt vmcnt(6)" ::: "memory");                       \
        __builtin_amdgcn_s_barrier();                                          \
        asm volatile("" ::: "memory");                                         \
    }                                                                          \
    cmp(n_k - 3);                                                              \
    asm volatile("s_waitcnt vmcnt(3)" ::: "memory");                           \
    __builtin_amdgcn_s_barrier();                                              \
    asm volatile("" ::: "memory");                                             \
    cmp(n_k - 2);                                                              \
    asm volatile("s_waitcnt vmcnt(0)" ::: "memory");                           \
    __builtin_amdgcn_s_barrier();                                              \
    asm volatile("" ::: "memory");                                             \
    cmp(n_k - 1);

// ---------- 2. output-projection GEMM ----------
__global__ __launch_bounds__(512, 2) void gemm_bt(const u16* __restrict__ A,
                                                  const u16* __restrict__ Bt,
                                                  float* __restrict__ C,
                                                  int M, int N, int K) {
    GEMM_RING_PROLOG(A, Bt, K)
    #pragma unroll
    for (int mt = 0; mt < 4; ++mt) {
        #pragma unroll
        for (int nt = 0; nt < 4; ++nt) {
            const long gr = m0 + wm + mt * 16 + quad * 4;
            const long gc = n0 + wn + nt * 16 + l15;
            #pragma unroll
            for (int r = 0; r < 4; ++r)
                C[(gr + r) * N + gc] = acc[mt][nt][r];
        }
    }
}

// ---------- 3. QKV GEMM, fused RMSNorm+RoPE+V-transpose epilogue ----------
// Epilogue unchanged from verified r8 form: per-wave 64x64 output, col0
// 64-aligned. K output chunk-XOR (^= key&7); V output P64 + chunk-XOR.
__global__ __launch_bounds__(512, 2) void gemm_qkv(const u16* __restrict__ A,
                                                   const u16* __restrict__ Bt,
                                                   const float* __restrict__ qw,
                                                   const float* __restrict__ kw,
                                                   const float2v* __restrict__ tab,
                                                   u16* __restrict__ Qr,
                                                   u16* __restrict__ Kr,
                                                   u16* __restrict__ Vt) {
    GEMM_RING_PROLOG(A, Bt, 2048)

    const int col0 = (int)n0 + wn;          // 64-aligned; whole wave in one zone
    if (col0 < 2560) {
        // ---- Q or K head: RMSNorm + RoPE ----
        const bool isQ = (col0 < 2048);
        const float* lw = isQ ? qw : kw;
        float wreg[4];
        #pragma unroll
        for (int nt = 0; nt < 4; ++nt) wreg[nt] = lw[nt * 16 + l15];
        const float qs = isQ ? 0.18033688011112042f : 1.0f;   // 0.125*log2(e) for Q
        const int swm = isQ ? 0 : 7;        // K rows get chunk-XOR by key&7
        u16* dst = isQ ? (Qr + ((size_t)(col0 >> 6)) * 2048 * 64)
                       : (Kr + ((size_t)((col0 - 2048) >> 6)) * 2048 * 64);
        const size_t head_stride = isQ ? ((size_t)32 * 2048 * 64) : ((size_t)8 * 2048 * 64);
        #pragma unroll
        for (int mt = 0; mt < 4; ++mt) {
            const int gr0 = (int)m0 + wm + mt * 16 + quad * 4;
            const int b = gr0 >> 11, tt0 = gr0 & 2047;
            float rms[4];
            #pragma unroll
            for (int r = 0; r < 4; ++r) {
                float s = 0.0f;
                #pragma unroll
                for (int nt = 0; nt < 4; ++nt) s += acc[mt][nt][r] * acc[mt][nt][r];
                s += __shfl_xor(s, 1);
                s += __shfl_xor(s, 2);
                s += __shfl_xor(s, 4);
                s += __shfl_xor(s, 8);
                rms[r] = rsqrtf(s * (1.0f / 64.0f) + 1e-5f);
            }
            u16* rowp = dst + (size_t)b * head_stride + (size_t)tt0 * 64;
            #pragma unroll
            for (int nt = 0; nt < 2; ++nt) {
                const int i = nt * 16 + l15;
                #pragma unroll
                for (int r = 0; r < 4; ++r) {
                    const float2v cs = tab[(tt0 + r) * 32 + i];
                    const float v1 = acc[mt][nt][r]     * rms[r] * wreg[nt];
                    const float v2 = acc[mt][nt + 2][r] * rms[r] * wreg[nt + 2];
                    const float o1 = (v1 * cs[0] - v2 * cs[1]) * qs;
                    const float o2 = (v2 * cs[0] + v1 * cs[1]) * qs;
                    const int k7 = (tt0 + r) & swm;
                    const int i1 = (((i >> 3) ^ k7) << 3) | (i & 7);
                    const int i2 = ((((i + 32) >> 3) ^ k7) << 3) | (i & 7);
                    rowp[(size_t)r * 64 + i1] = f2bf(o1);
                    rowp[(size_t)r * 64 + i2] = f2bf(o2);
                }
            }
        }
    } else {
        // ---- V head: transpose to [head][d][t'], t' = P64-swizzled within 64-key group ----
        const int kh = (col0 - 2560) >> 6;
        #pragma unroll
        for (int mt = 0; mt < 4; ++mt) {
            const int gr0 = (int)m0 + wm + mt * 16 + quad * 4;
            const int b = gr0 >> 11, tt0 = gr0 & 2047;
            const int tb = tt0 & ~63;
            const int tl = tt0 & 63;
            const int p0b = ((tl & 15) >> 2) * 16 + (tl >> 4) * 4;   // P64(tl), low2=0
            #pragma unroll
            for (int nt = 0; nt < 4; ++nt) {
                const int d = nt * 16 + l15;
                ushort4v o;
                #pragma unroll
                for (int r = 0; r < 4; ++r) o[r] = f2bf(acc[mt][nt][r]);
                const int col = tb + ((((p0b >> 3) ^ (d & 7)) << 3) | (p0b & 7));
                *(ushort4v*)(Vt + (((size_t)(b * 8 + kh)) * 64 + d) * 2048 + col) = o;
            }
        }
    }
}

// ---------- 4. flash attention: fixed-max softmax (no running max/rescale) ----------
// 4 waves x 2 q-frags, 64-key tiles, 1024 blocks, gl_lds, pre-baked
// conflict-free layouts. Softmax max-tracking eliminated: |S| <= 64*0.125*
// log2e = 11.54 (Cauchy-Schwarz, log2 domain); fixed M0=12, l pure sum.
#define SOFTMAX_PACK(S, l_i, pf)                                            \
    {                                                                       \
        float rs = 0.0f;                                                    \
        _Pragma("unroll")                                                   \
        for (int nt = 0; nt < 4; ++nt)                                      \
            _Pragma("unroll")                                               \
            for (int r = 0; r < 4; ++r) {                                   \
                const float pv = __builtin_amdgcn_exp2f(S[nt][r] - 12.0f);  \
                S[nt][r] = pv;                                              \
                rs += pv;                                                   \
            }                                                               \
        l_i += rs;                                                          \
        _Pragma("unroll")                                                   \
        for (int nt = 0; nt < 4; ++nt) {                                    \
            union { uint32_t u[2]; short4v s; } pu;                         \
            pu.u[0] = pack_bf16x2(S[nt][0], S[nt][1]);                      \
            pu.u[1] = pack_bf16x2(S[nt][2], S[nt][3]);                      \
            pf[nt] = pu.s;                                                  \
        }                                                                   \
    }

#define WRITE_O(O, l_i, qrow)                                               \
    {                                                                       \
        float lt = l_i;                                                     \
        lt += __shfl_xor(lt, 16);                                           \
        lt += __shfl_xor(lt, 32);                                           \
        const float rl = 1.0f / lt;                                         \
        _Pragma("unroll")                                                   \
        for (int dt = 0; dt < 4; ++dt) {                                    \
            ushort4v o;                                                     \
            _Pragma("unroll")                                               \
            for (int r = 0; r < 4; ++r) o[r] = f2bf(O[dt][r] * rl);         \
            *(ushort4v*)(Ob + ((size_t)(b * 2048 + (qrow))) * 2048 +        \
                         h * 64 + dt * 16 + quad * 4) = o;                  \
        }                                                                   \
    }

__global__ __launch_bounds__(256, 4) void attn_fwd(const u16* __restrict__ Qr,
                                                   const u16* __restrict__ Kr,
                                                   const u16* __restrict__ Vt,
                                                   u16* __restrict__ Ob) {
    __shared__ u16 lds_k[2][64 * 64];    // [key][swz 16B-chunk of d]        8KB x2
    __shared__ u16 lds_v[2][64 * 64];    // [d][swz 16B-chunk of P64(key)]   8KB x2
    const int tid  = threadIdx.x;
    const int wave = tid >> 6;              // 0..3
    const int lane = tid & 63;
    const int quad = lane >> 4;
    const int l15  = lane & 15;
    const int sw7  = l15 & 7;
    const int qx = 15 - blockIdx.y;         // 15..0, longest blocks dispatched first
    const int bh = blockIdx.x;              // 0..63 (fast dim: head locality per XCD)
    const int b = bh >> 5, h = bh & 31;
    const int kh = h >> 2;
    const u16* Qh = Qr + ((size_t)(b * 32 + h))  * 2048 * 64;
    const u16* Kh = Kr + ((size_t)(b * 8 + kh))  * 2048 * 64;
    const u16* Vh = Vt + ((size_t)(b * 8 + kh))  * 64 * 2048;

    const int qrow_c0 = qx * 128 + wave * 32 + l15;
    const int qrow_c1 = qrow_c0 + 16;
    short8 qf[2][2];   // [frag][ks]
    #pragma unroll
    for (int ks = 0; ks < 2; ++ks) {
        qf[0][ks] = *(const short8*)(Qh + (size_t)qrow_c0 * 64 + ks * 32 + quad * 8);
        qf[1][ks] = *(const short8*)(Qh + (size_t)qrow_c1 * 64 + ks * 32 + quad * 8);
    }

    float l0v = 0.0f, l1v = 0.0f;
    float4v O0[4], O1[4];
    #pragma unroll
    for (int dt = 0; dt < 4; ++dt)
        #pragma unroll
        for (int r = 0; r < 4; ++r) { O0[dt][r] = 0.0f; O1[dt][r] = 0.0f; }

    // stage one 64-key tile (K 8KB + V 8KB) into buffer pb, key base k0
    const int vrow = tid >> 3;              // 0..31 (+ j*32)
    const int vchk = (tid & 7) * 8;         // u16 chunk offset within 64-key row
    auto stage = [&](int pb, int k0) {
        #pragma unroll
        for (int j = 0; j < 2; ++j)
            gl_lds16(Kh + (size_t)k0 * 64 + (j * 256 + tid) * 8,
                     &lds_k[pb][(j * 256 + tid) * 8]);
        #pragma unroll
        for (int j = 0; j < 2; ++j)
            gl_lds16(Vh + (size_t)(j * 32 + vrow) * 2048 + k0 + vchk,
                     &lds_v[pb][(j * 256 + tid) * 8]);
    };
    stage(0, 0);
    __syncthreads();

    const int n_it = 2 * qx + 2;            // 64-key tiles in this block's causal span
    for (int i = 0; i < n_it; ++i) {
        const int p = i & 1;
        const int kt0 = i << 6;

        if (i + 1 < n_it) stage(1 - p, (i + 1) << 6);

        float4v S0[4], S1[4];
        #pragma unroll
        for (int nt = 0; nt < 4; ++nt)
            #pragma unroll
            for (int r = 0; r < 4; ++r) { S0[nt][r] = 0.0f; S1[nt][r] = 0.0f; }
        __builtin_amdgcn_s_setprio(1);
        #pragma unroll
        for (int ks = 0; ks < 2; ++ks) {
            #pragma unroll
            for (int nt = 0; nt < 4; ++nt) {
                short8 kf = *(const short8*)(lds_k[p] + (nt * 16 + l15) * 64 +
                                             (((ks * 4 + quad) ^ sw7) << 3));
                S0[nt] = __builtin_amdgcn_mfma_f32_16x16x32_bf16(kf, qf[0][ks], S0[nt], 0, 0, 0);
                S1[nt] = __builtin_amdgcn_mfma_f32_16x16x32_bf16(kf, qf[1][ks], S1[nt], 0, 0, 0);
            }
        }
        __builtin_amdgcn_s_setprio(0);

        // diagonal straddles the last two 64-key tiles
        if (i >= n_it - 2) {
            #pragma unroll
            for (int nt = 0; nt < 4; ++nt) {
                const int keyb = kt0 + nt * 16 + quad * 4;
                #pragma unroll
                for (int r = 0; r < 4; ++r) {
                    if (keyb + r > qrow_c0) S0[nt][r] = -3e38f;
                    if (keyb + r > qrow_c1) S1[nt][r] = -3e38f;
                }
            }
        }

        short4v pf0[4], pf1[4];
        SOFTMAX_PACK(S0, l0v, pf0);
        SOFTMAX_PACK(S1, l1v, pf1);

        __builtin_amdgcn_s_setprio(1);
        #pragma unroll
        for (int nt2 = 0; nt2 < 2; ++nt2) {
            #pragma unroll
            for (int dt = 0; dt < 4; ++dt) {
                short8 vv = *(const short8*)(lds_v[p] + (dt * 16 + l15) * 64 +
                                             (((quad * 2 + nt2) ^ sw7) << 3));
                short4v vlo = __builtin_shufflevector(vv, vv, 0, 1, 2, 3);
                short4v vhi = __builtin_shufflevector(vv, vv, 4, 5, 6, 7);
                O0[dt] = __builtin_amdgcn_mfma_f32_16x16x16bf16_1k(vlo, pf0[2 * nt2],     O0[dt], 0, 0, 0);
                O0[dt] = __builtin_amdgcn_mfma_f32_16x16x16bf16_1k(vhi, pf0[2 * nt2 + 1], O0[dt], 0, 0, 0);
                O1[dt] = __builtin_amdgcn_mfma_f32_16x16x16bf16_1k(vlo, pf1[2 * nt2],     O1[dt], 0, 0, 0);
                O1[dt] = __builtin_amdgcn_mfma_f32_16x16x16bf16_1k(vhi, pf1[2 * nt2 + 1], O1[dt], 0, 0, 0);
            }
        }
        __builtin_amdgcn_s_setprio(0);

        __syncthreads();
    }
    WRITE_O(O0, l0v, qrow_c0);
    WRITE_O(O1, l1v, qrow_c1);
}

// ---------- launcher ----------
extern "C" void kernel_launch(void* const* d_in, const int* in_sizes, int n_in,
                              void* d_out, int out_size, void* d_ws, size_t ws_size,
                              hipStream_t stream) {
    (void)in_sizes; (void)n_in; (void)out_size; (void)ws_size;
    const float* x  = (const float*)d_in[0];
    const float* Wq = (const float*)d_in[1];
    const float* Wk = (const float*)d_in[2];
    const float* Wv = (const float*)d_in[3];
    const float* Wo = (const float*)d_in[4];
    const float* qw = (const float*)d_in[5];
    const float* kw = (const float*)d_in[6];
    float* out = (float*)d_out;

    char* ws = (char*)d_ws;
    size_t off = 0;
    auto alloc = [&](size_t bytes) {
        char* p = ws + off;
        off += (bytes + 255) & ~(size_t)255;
        return p;
    };
    u16* xb     = (u16*)alloc((size_t)8388608 * 2);        // x bf16       16 MB
    u16* wqkv_t = (u16*)alloc((size_t)3072 * 2048 * 2);    // [n][k]       12 MB
    u16* wo_t   = (u16*)alloc((size_t)2048 * 2048 * 2);    //               8 MB
    u16* q_r    = (u16*)alloc((size_t)2 * 32 * 2048 * 64 * 2);  // 16 MB
    u16* k_r    = (u16*)alloc((size_t)2 * 8 * 2048 * 64 * 2);   //  4 MB (chunk-swizzled)
    u16* v_r    = (u16*)alloc((size_t)2 * 8 * 64 * 2048 * 2);   //  4 MB (d-major, P64+XOR swz)
    float2v* rtab = (float2v*)alloc((size_t)2048 * 32 * 8);     // 512 KB
    u16* attnb  = xb;   // reuse: xb dead after gemm_qkv

    hipLaunchKernelGGL(prep, dim3(13568), dim3(256), 0, stream,
                       (const float4v*)x, Wq, Wk, Wv, Wo,
                       (ushort4v*)xb, wqkv_t, wo_t, rtab);
    hipLaunchKernelGGL(gemm_qkv, dim3(16, 24), dim3(512), 0, stream,
                       xb, wqkv_t, qw, kw, rtab, q_r, k_r, v_r);
    hipLaunchKernelGGL(attn_fwd, dim3(64, 16), dim3(256), 0, stream, q_r, k_r, v_r, attnb);
    hipLaunchKernelGGL(gemm_bt, dim3(16, 16), dim3(512), 0, stream,
                       attnb, wo_t, out, 4096, 2048, 2048);
}

// Round 12
// 278.322 us; speedup vs baseline: 1.0379x; 1.0379x over previous
//
#include <hip/hip_runtime.h>
#include <cstdint>
#include <cstddef>

typedef unsigned short u16;
typedef __attribute__((ext_vector_type(8))) short short8;    // 8 bf16 (4 VGPRs) MFMA A/B frag (x32)
typedef __attribute__((ext_vector_type(4))) short short4v;   // 4 bf16 (2 VGPRs) MFMA A/B frag (x16)
typedef __attribute__((ext_vector_type(4))) float float4v;   // MFMA C/D frag
typedef __attribute__((ext_vector_type(4))) unsigned short ushort4v;
typedef __attribute__((ext_vector_type(2))) float float2v;

// ---------- helpers ----------
__device__ __forceinline__ u16 f2bf(float f) {
    union { float f; uint32_t u; } x; x.f = f;
    uint32_t r = x.u + 0x7fffu + ((x.u >> 16) & 1u);   // RTNE
    return (u16)(r >> 16);
}
__device__ __forceinline__ uint32_t pack_bf16x2(float lo, float hi) {
    union { float f; uint32_t u; } a, b; a.f = lo; b.f = hi;
    return __builtin_amdgcn_perm(b.u + 0x8000u, a.u + 0x8000u, 0x07060302u);
}
// async global->LDS, 16B per lane (HW: wave-uniform base + lane*16)
__device__ __forceinline__ void gl_lds16(const u16* g, u16* l) {
    __builtin_amdgcn_global_load_lds(
        (const __attribute__((address_space(1))) void*)g,
        (__attribute__((address_space(3))) void*)l, 16, 0, 0);
}

// ---------- 1. merged prep: cast x, rope table, weight transposes ----------
__global__ __launch_bounds__(256) void prep(const float4v* __restrict__ x,
                                            const float* __restrict__ Wq,
                                            const float* __restrict__ Wk,
                                            const float* __restrict__ Wv,
                                            const float* __restrict__ Wo,
                                            ushort4v* __restrict__ xb,
                                            u16* __restrict__ wqkv_t,
                                            u16* __restrict__ wo_t,
                                            float2v* __restrict__ tab) {
    __shared__ float lds[64][33];
    const int bid = blockIdx.x;
    const int tid = threadIdx.x;
    if (bid < 8192) {
        const int i = bid * 256 + tid;
        float4v v = x[i];
        ushort4v o;
        #pragma unroll
        for (int j = 0; j < 4; ++j) o[j] = f2bf(v[j]);
        xb[i] = o;
        return;
    }
    if (bid < 8448) {
        const int idx = (bid - 8192) * 256 + tid;   // 65536
        const int t = idx >> 5;
        const int i = idx & 31;
        const float invf = exp2f(-(float)i * (19.931568569324174f / 32.0f));
        float sv, cv;
        sincosf((float)t * invf, &sv, &cv);
        float2v o; o[0] = cv; o[1] = sv;
        tab[idx] = o;
        return;
    }
    const float* src;
    int Ns, n0, k0, scol0;
    u16* dst;
    if (bid < 11520) {                       // 3072 wqkv blocks (96 n x 32 k64)
        const int id = bid - 8448;
        const int bx = id % 96, by = id / 96;
        n0 = bx * 32; k0 = by * 64;
        if (n0 < 2048)      { src = Wq; Ns = 2048; scol0 = n0; }
        else if (n0 < 2560) { src = Wk; Ns = 512;  scol0 = n0 - 2048; }
        else                { src = Wv; Ns = 512;  scol0 = n0 - 2560; }
        dst = wqkv_t;
    } else {                                 // 2048 wo blocks (64 n x 32 k64)
        const int id = bid - 11520;
        const int bx = id & 63, by = id >> 6;
        n0 = bx * 32; k0 = by * 64;
        src = Wo; Ns = 2048; scol0 = n0;
        dst = wo_t;
    }
    const int row64 = tid >> 2;              // k local, 0..63
    const int c8    = (tid & 3) * 8;         // n local, 0,8,16,24
    const float* sp = src + (size_t)(k0 + row64) * Ns + scol0 + c8;
    const float4v va = *(const float4v*)sp;
    const float4v vb = *(const float4v*)(sp + 4);
    #pragma unroll
    for (int i = 0; i < 4; ++i) { lds[row64][c8 + i] = va[i]; lds[row64][c8 + 4 + i] = vb[i]; }
    __syncthreads();
    const int nrow = tid >> 3;               // n local, 0..31
    const int kk   = (tid & 7) * 8;          // k local, 0..56
    short8 o8;
    #pragma unroll
    for (int i = 0; i < 8; ++i) o8[i] = (short)f2bf(lds[kk + i][nrow]);
    *(short8*)(dst + (size_t)(n0 + nrow) * 2048 + k0 + kk) = o8;
}

// ---------- 2. output-projection GEMM, m97 structure (r8 known-good form) ----------
__global__ __launch_bounds__(256, 3) void gemm_bt(const u16* __restrict__ A,
                                                  const u16* __restrict__ Bt,
                                                  float* __restrict__ C,
                                                  int M, int N, int K) {
    __shared__ u16 lds_a[128 * 32];
    __shared__ u16 lds_b[128 * 32];
    const int tid  = threadIdx.x;
    const int wave = tid >> 6;
    const int lane = tid & 63;
    const int quad = lane >> 4;
    const int l15  = lane & 15;
    const long m0 = (long)blockIdx.x * 128;
    const long n0 = (long)blockIdx.y * 128;
    const int wm = (wave >> 1) * 64;
    const int wn = (wave & 1) * 64;
    const int s_row = tid >> 2;
    const int s_col = (tid & 3) * 8;

    float4v acc[4][4];
    #pragma unroll
    for (int i = 0; i < 4; ++i)
        #pragma unroll
        for (int j = 0; j < 4; ++j)
            #pragma unroll
            for (int r = 0; r < 4; ++r) acc[i][j][r] = 0.0f;

    const u16* ga0 = A  + (m0 + s_row) * (long)K + s_col;
    const u16* ga1 = ga0 + 64 * (long)K;
    const u16* gb0 = Bt + (n0 + s_row) * (long)K + s_col;
    const u16* gb1 = gb0 + 64 * (long)K;
    u16* la = lds_a + tid * 8;
    u16* lb = lds_b + tid * 8;

    const int n_k = K >> 5;
    for (int it = 0; it < n_k; ++it) {
        const int k0 = it << 5;
        gl_lds16(ga0 + k0, la);
        gl_lds16(ga1 + k0, la + 2048);
        gl_lds16(gb0 + k0, lb);
        gl_lds16(gb1 + k0, lb + 2048);
        __syncthreads();
        short8 af[4], bfr[4];
        #pragma unroll
        for (int mt = 0; mt < 4; ++mt)
            af[mt] = *(const short8*)(lds_a + (wm + mt * 16 + l15) * 32 + quad * 8);
        #pragma unroll
        for (int nt = 0; nt < 4; ++nt)
            bfr[nt] = *(const short8*)(lds_b + (wn + nt * 16 + l15) * 32 + quad * 8);
        #pragma unroll
        for (int mt = 0; mt < 4; ++mt)
            #pragma unroll
            for (int nt = 0; nt < 4; ++nt)
                acc[mt][nt] = __builtin_amdgcn_mfma_f32_16x16x32_bf16(af[mt], bfr[nt], acc[mt][nt], 0, 0, 0);
        __syncthreads();
    }
    #pragma unroll
    for (int mt = 0; mt < 4; ++mt) {
        #pragma unroll
        for (int nt = 0; nt < 4; ++nt) {
            const long gr = m0 + wm + mt * 16 + quad * 4;
            const long gc = n0 + wn + nt * 16 + l15;
            #pragma unroll
            for (int r = 0; r < 4; ++r)
                C[(gr + r) * N + gc] = acc[mt][nt][r];
        }
    }
}

// ---------- 3. QKV GEMM: 8-phase 256x256 pipelined template (m201 port) ----------
// BM=BN=256, BK=64, 512 thr = 8 waves (2M x 4N, m-interleaved: wave wr owns
// rows wr*64 and 128+wr*64). LDS 128KB = 2 bufs x (A[256][64] + B[256][64]).
// Per phase: {ds_read reg subtile; stage 1 half-tile (2 gl_lds/thr); barrier;
// lgkmcnt(0); 16 MFMA; barrier}. vmcnt(6) ONLY at phases 4/8 (3 half-tiles in
// flight); drain-0 only in the last iteration. Region-lifetime schedule:
//   consumed: Ah0@p1, Bh0/Bh1@p2 (B frags held in regs across m-halves), Ah1@p3
//   staged:   p1:(t+1).Ah1  p2:(t+2).Ah0  p3:(t+2).Bh0  p4:(t+2).Bh1
//             p5:(t+2).Ah1  p6:(t+3).Ah0  p7:(t+3).Bh0  p8:(t+3).Bh1
// T2 swizzle: LDS chunk pc = lc ^ (row&7), realized by pre-swizzling the
// gl_lds SOURCE address (LDS dest stays lane-linear, rule #21).
#define ACCL(mh, mt, nl) acc[mh][mt][(nl) >> 1][(nl) & 1]

__device__ __forceinline__ void gemm256_pipe(const u16* __restrict__ A,
                                             const u16* __restrict__ B,
                                             const int K, const int nkt,
                                             u16* lds, const int tid,
                                             const long m0, const long n0,
                                             float4v acc[2][4][2][2]) {
    const int wave = tid >> 6;
    const int lane = tid & 63;
    const int quad = lane >> 4;
    const int l15  = lane & 15;
    const int wr = wave >> 2;          // 0..1
    const int wc = wave & 3;           // 0..3
    const int sw7 = l15 & 7;

    #pragma unroll
    for (int a = 0; a < 2; ++a)
        #pragma unroll
        for (int b = 0; b < 4; ++b)
            #pragma unroll
            for (int c = 0; c < 2; ++c)
                #pragma unroll
                for (int d = 0; d < 2; ++d)
                    #pragma unroll
                    for (int r = 0; r < 4; ++r) acc[a][b][c][d][r] = 0.0f;

    // stage one half-tile: type 0=A,1=B; h half; kt K-tile. 2 gl_lds/thread.
    auto stg = [&](int kt, int type, int h) {
        if (kt >= nkt) return;
        u16* dst = lds + (kt & 1) * 32768 + type * 16384 + h * 8192;
        const u16* src = type ? B : A;
        const long r0 = (type ? n0 : m0) + h * 128;
        const long k0 = (long)kt << 6;
        #pragma unroll
        for (int j = 0; j < 2; ++j) {
            const int cid = tid + j * 512;
            const int row = cid >> 3;
            const int lc  = (cid & 7) ^ (row & 7);    // inverse swizzle on source
            gl_lds16(src + (r0 + row) * (long)K + k0 + lc * 8, dst + cid * 8);
        }
    };
    short8 aA[4][2], bB0[2][2], bB1[2][2];
    auto rdA = [&](int b, int mh) {
        const u16* base = lds + b * 32768;
        #pragma unroll
        for (int mt = 0; mt < 4; ++mt) {
            const int row = mh * 128 + wr * 64 + mt * 16 + l15;
            #pragma unroll
            for (int kk = 0; kk < 2; ++kk)
                aA[mt][kk] = *(const short8*)(base + row * 64 + (((kk * 4 + quad) ^ sw7) << 3));
        }
    };
    auto rdB = [&](int b, int nh, short8 (&bb)[2][2]) {
        const u16* base = lds + b * 32768 + 16384;
        #pragma unroll
        for (int nt = 0; nt < 2; ++nt) {
            const int row = wc * 64 + nh * 32 + nt * 16 + l15;
            #pragma unroll
            for (int kk = 0; kk < 2; ++kk)
                bb[nt][kk] = *(const short8*)(base + row * 64 + (((kk * 4 + quad) ^ sw7) << 3));
        }
    };
    auto mm = [&](int mh, int nh, short8 (&bb)[2][2]) {
        __builtin_amdgcn_s_setprio(1);
        #pragma unroll
        for (int mt = 0; mt < 4; ++mt)
            #pragma unroll
            for (int nt = 0; nt < 2; ++nt)
                #pragma unroll
                for (int kk = 0; kk < 2; ++kk)
                    acc[mh][mt][nh][nt] = __builtin_amdgcn_mfma_f32_16x16x32_bf16(
                        aA[mt][kk], bb[nt][kk], acc[mh][mt][nh][nt], 0, 0, 0);
        __builtin_amdgcn_s_setprio(0);
    };
    #define GFENCE asm volatile("" ::: "memory")
    #define GBAR() do { GFENCE; __builtin_amdgcn_s_barrier(); GFENCE; } while (0)
    #define GLG0() do { asm volatile("s_waitcnt lgkmcnt(0)" ::: "memory"); \
                        __builtin_amdgcn_sched_barrier(0); } while (0)

    // prologue: t0 fully + t1 {Ah0,Bh0,Bh1}; vmcnt(6) leaves t1's 3 in flight
    stg(0, 0, 0); stg(0, 1, 0); stg(0, 1, 1); stg(0, 0, 1);
    stg(1, 0, 0); stg(1, 1, 0); stg(1, 1, 1);
    asm volatile("s_waitcnt vmcnt(6)" ::: "memory");
    GBAR();

    for (int t = 0; t < nkt; t += 2) {
        const bool lastIt = (t + 2 >= nkt);
        // p1: compute (mh0,nh0) of tile t
        rdA(0, 0); rdB(0, 0, bB0); stg(t + 1, 0, 1);
        GBAR(); GLG0(); mm(0, 0, bB0); GBAR();
        // p2: (mh0,nh1)
        rdB(0, 1, bB1); stg(t + 2, 0, 0);
        GBAR(); GLG0(); mm(0, 1, bB1); GBAR();
        // p3: (mh1,nh1)
        rdA(0, 1); stg(t + 2, 1, 0);
        GBAR(); GLG0(); mm(1, 1, bB1); GBAR();
        // p4: (mh1,nh0) -- regs only; vmcnt gate for tile t+1
        stg(t + 2, 1, 1);
        if (lastIt) { asm volatile("s_waitcnt vmcnt(0)" ::: "memory"); }
        else        { asm volatile("s_waitcnt vmcnt(6)" ::: "memory"); }
        GBAR(); mm(1, 0, bB0); GBAR();
        // p5: tile t+1, (mh0,nh0)
        rdA(1, 0); rdB(1, 0, bB0); stg(t + 2, 0, 1);
        GBAR(); GLG0(); mm(0, 0, bB0); GBAR();
        // p6
        rdB(1, 1, bB1); stg(t + 3, 0, 0);
        GBAR(); GLG0(); mm(0, 1, bB1); GBAR();
        // p7
        rdA(1, 1); stg(t + 3, 1, 0);
        GBAR(); GLG0(); mm(1, 1, bB1); GBAR();
        // p8
        stg(t + 3, 1, 1);
        if (lastIt) { asm volatile("s_waitcnt vmcnt(0)" ::: "memory"); }
        else        { asm volatile("s_waitcnt vmcnt(6)" ::: "memory"); }
        GBAR(); mm(1, 0, bB0); GBAR();
    }
}

__global__ __launch_bounds__(512) void gemm_qkv(const u16* __restrict__ A,
                                                const u16* __restrict__ Bt,
                                                const float* __restrict__ qw,
                                                const float* __restrict__ kw,
                                                const float2v* __restrict__ tab,
                                                u16* __restrict__ Qr,
                                                u16* __restrict__ Kr,
                                                u16* __restrict__ Vt) {
    __shared__ u16 lds[65536];               // 128 KiB: 2 bufs x (A 32KB + B 32KB)
    const int tid = threadIdx.x;
    const int lane = tid & 63;
    const int quad = lane >> 4;
    const int l15  = lane & 15;
    const int wr = (tid >> 6) >> 2;
    const int wc = (tid >> 6) & 3;
    const long m0 = (long)blockIdx.x * 256;
    const long n0 = (long)blockIdx.y * 256;

    float4v acc[2][4][2][2];
    gemm256_pipe(A, Bt, 2048, 32, lds, tid, m0, n0, acc);

    const int col0 = (int)n0 + wc * 64;      // 64-aligned; whole wave in one zone
    if (col0 < 2560) {
        // ---- Q or K head: RMSNorm + RoPE ----
        const bool isQ = (col0 < 2048);
        const float* lw = isQ ? qw : kw;
        float wreg[4];
        #pragma unroll
        for (int nl = 0; nl < 4; ++nl) wreg[nl] = lw[nl * 16 + l15];
        const float qs = isQ ? 0.18033688011112042f : 1.0f;   // 0.125*log2(e) for Q
        const int swm = isQ ? 0 : 7;         // K rows get chunk-XOR by key&7
        u16* dst = isQ ? (Qr + ((size_t)(col0 >> 6)) * 2048 * 64)
                       : (Kr + ((size_t)((col0 - 2048) >> 6)) * 2048 * 64);
        const size_t head_stride = isQ ? ((size_t)32 * 2048 * 64) : ((size_t)8 * 2048 * 64);
        #pragma unroll
        for (int mh = 0; mh < 2; ++mh) {
            #pragma unroll
            for (int mt = 0; mt < 4; ++mt) {
                const int gr0 = (int)m0 + mh * 128 + wr * 64 + mt * 16 + quad * 4;
                const int b = gr0 >> 11, tt0 = gr0 & 2047;
                float rms[4];
                #pragma unroll
                for (int r = 0; r < 4; ++r) {
                    float s = 0.0f;
                    #pragma unroll
                    for (int nl = 0; nl < 4; ++nl) s += ACCL(mh, mt, nl)[r] * ACCL(mh, mt, nl)[r];
                    s += __shfl_xor(s, 1);
                    s += __shfl_xor(s, 2);
                    s += __shfl_xor(s, 4);
                    s += __shfl_xor(s, 8);
                    rms[r] = rsqrtf(s * (1.0f / 64.0f) + 1e-5f);
                }
                u16* rowp = dst + (size_t)b * head_stride + (size_t)tt0 * 64;
                #pragma unroll
                for (int nl = 0; nl < 2; ++nl) {
                    const int i = nl * 16 + l15;
                    #pragma unroll
                    for (int r = 0; r < 4; ++r) {
                        const float2v cs = tab[(tt0 + r) * 32 + i];
                        const float v1 = ACCL(mh, mt, nl)[r]     * rms[r] * wreg[nl];
                        const float v2 = ACCL(mh, mt, nl + 2)[r] * rms[r] * wreg[nl + 2];
                        const float o1 = (v1 * cs[0] - v2 * cs[1]) * qs;
                        const float o2 = (v2 * cs[0] + v1 * cs[1]) * qs;
                        const int k7 = (tt0 + r) & swm;
                        const int i1 = (((i >> 3) ^ k7) << 3) | (i & 7);
                        const int i2 = ((((i + 32) >> 3) ^ k7) << 3) | (i & 7);
                        rowp[(size_t)r * 64 + i1] = f2bf(o1);
                        rowp[(size_t)r * 64 + i2] = f2bf(o2);
                    }
                }
            }
        }
    } else {
        // ---- V head: transpose to [head][d][t'], t' = P64-swizzled within 64-key group ----
        const int kh = (col0 - 2560) >> 6;
        #pragma unroll
        for (int mh = 0; mh < 2; ++mh) {
            #pragma unroll
            for (int mt = 0; mt < 4; ++mt) {
                const int gr0 = (int)m0 + mh * 128 + wr * 64 + mt * 16 + quad * 4;
                const int b = gr0 >> 11, tt0 = gr0 & 2047;
                const int tb = tt0 & ~63;
                const int tl = tt0 & 63;
                const int p0b = ((tl & 15) >> 2) * 16 + (tl >> 4) * 4;   // P64(tl)
                #pragma unroll
                for (int nl = 0; nl < 4; ++nl) {
                    const int d = nl * 16 + l15;
                    ushort4v o;
                    #pragma unroll
                    for (int r = 0; r < 4; ++r) o[r] = f2bf(ACCL(mh, mt, nl)[r]);
                    const int col = tb + ((((p0b >> 3) ^ (d & 7)) << 3) | (p0b & 7));
                    *(ushort4v*)(Vt + (((size_t)(b * 8 + kh)) * 64 + d) * 2048 + col) = o;
                }
            }
        }
    }
}

// ---------- 4. flash attention: fixed-max softmax (no running max/rescale) ----------
#define SOFTMAX_PACK(S, l_i, pf)                                            \
    {                                                                       \
        float rs = 0.0f;                                                    \
        _Pragma("unroll")                                                   \
        for (int nt = 0; nt < 4; ++nt)                                      \
            _Pragma("unroll")                                               \
            for (int r = 0; r < 4; ++r) {                                   \
                const float pv = __builtin_amdgcn_exp2f(S[nt][r] - 12.0f);  \
                S[nt][r] = pv;                                              \
                rs += pv;                                                   \
            }                                                               \
        l_i += rs;                                                          \
        _Pragma("unroll")                                                   \
        for (int nt = 0; nt < 4; ++nt) {                                    \
            union { uint32_t u[2]; short4v s; } pu;                         \
            pu.u[0] = pack_bf16x2(S[nt][0], S[nt][1]);                      \
            pu.u[1] = pack_bf16x2(S[nt][2], S[nt][3]);                      \
            pf[nt] = pu.s;                                                  \
        }                                                                   \
    }

#define WRITE_O(O, l_i, qrow)                                               \
    {                                                                       \
        float lt = l_i;                                                     \
        lt += __shfl_xor(lt, 16);                                           \
        lt += __shfl_xor(lt, 32);                                           \
        const float rl = 1.0f / lt;                                         \
        _Pragma("unroll")                                                   \
        for (int dt = 0; dt < 4; ++dt) {                                    \
            ushort4v o;                                                     \
            _Pragma("unroll")                                               \
            for (int r = 0; r < 4; ++r) o[r] = f2bf(O[dt][r] * rl);         \
            *(ushort4v*)(Ob + ((size_t)(b * 2048 + (qrow))) * 2048 +        \
                         h * 64 + dt * 16 + quad * 4) = o;                  \
        }                                                                   \
    }

__global__ __launch_bounds__(256, 4) void attn_fwd(const u16* __restrict__ Qr,
                                                   const u16* __restrict__ Kr,
                                                   const u16* __restrict__ Vt,
                                                   u16* __restrict__ Ob) {
    __shared__ u16 lds_k[2][64 * 64];
    __shared__ u16 lds_v[2][64 * 64];
    const int tid  = threadIdx.x;
    const int wave = tid >> 6;
    const int lane = tid & 63;
    const int quad = lane >> 4;
    const int l15  = lane & 15;
    const int sw7  = l15 & 7;
    const int qx = 15 - blockIdx.y;
    const int bh = blockIdx.x;
    const int b = bh >> 5, h = bh & 31;
    const int kh = h >> 2;
    const u16* Qh = Qr + ((size_t)(b * 32 + h))  * 2048 * 64;
    const u16* Kh = Kr + ((size_t)(b * 8 + kh))  * 2048 * 64;
    const u16* Vh = Vt + ((size_t)(b * 8 + kh))  * 64 * 2048;

    const int qrow_c0 = qx * 128 + wave * 32 + l15;
    const int qrow_c1 = qrow_c0 + 16;
    short8 qf[2][2];
    #pragma unroll
    for (int ks = 0; ks < 2; ++ks) {
        qf[0][ks] = *(const short8*)(Qh + (size_t)qrow_c0 * 64 + ks * 32 + quad * 8);
        qf[1][ks] = *(const short8*)(Qh + (size_t)qrow_c1 * 64 + ks * 32 + quad * 8);
    }

    float l0v = 0.0f, l1v = 0.0f;
    float4v O0[4], O1[4];
    #pragma unroll
    for (int dt = 0; dt < 4; ++dt)
        #pragma unroll
        for (int r = 0; r < 4; ++r) { O0[dt][r] = 0.0f; O1[dt][r] = 0.0f; }

    const int vrow = tid >> 3;
    const int vchk = (tid & 7) * 8;
    auto stage = [&](int pb, int k0) {
        #pragma unroll
        for (int j = 0; j < 2; ++j)
            gl_lds16(Kh + (size_t)k0 * 64 + (j * 256 + tid) * 8,
                     &lds_k[pb][(j * 256 + tid) * 8]);
        #pragma unroll
        for (int j = 0; j < 2; ++j)
            gl_lds16(Vh + (size_t)(j * 32 + vrow) * 2048 + k0 + vchk,
                     &lds_v[pb][(j * 256 + tid) * 8]);
    };
    stage(0, 0);
    __syncthreads();

    const int n_it = 2 * qx + 2;
    for (int i = 0; i < n_it; ++i) {
        const int p = i & 1;
        const int kt0 = i << 6;

        if (i + 1 < n_it) stage(1 - p, (i + 1) << 6);

        float4v S0[4], S1[4];
        #pragma unroll
        for (int nt = 0; nt < 4; ++nt)
            #pragma unroll
            for (int r = 0; r < 4; ++r) { S0[nt][r] = 0.0f; S1[nt][r] = 0.0f; }
        __builtin_amdgcn_s_setprio(1);
        #pragma unroll
        for (int ks = 0; ks < 2; ++ks) {
            #pragma unroll
            for (int nt = 0; nt < 4; ++nt) {
                short8 kf = *(const short8*)(lds_k[p] + (nt * 16 + l15) * 64 +
                                             (((ks * 4 + quad) ^ sw7) << 3));
                S0[nt] = __builtin_amdgcn_mfma_f32_16x16x32_bf16(kf, qf[0][ks], S0[nt], 0, 0, 0);
                S1[nt] = __builtin_amdgcn_mfma_f32_16x16x32_bf16(kf, qf[1][ks], S1[nt], 0, 0, 0);
            }
        }
        __builtin_amdgcn_s_setprio(0);

        if (i >= n_it - 2) {
            #pragma unroll
            for (int nt = 0; nt < 4; ++nt) {
                const int keyb = kt0 + nt * 16 + quad * 4;
                #pragma unroll
                for (int r = 0; r < 4; ++r) {
                    if (keyb + r > qrow_c0) S0[nt][r] = -3e38f;
                    if (keyb + r > qrow_c1) S1[nt][r] = -3e38f;
                }
            }
        }

        short4v pf0[4], pf1[4];
        SOFTMAX_PACK(S0, l0v, pf0);
        SOFTMAX_PACK(S1, l1v, pf1);

        __builtin_amdgcn_s_setprio(1);
        #pragma unroll
        for (int nt2 = 0; nt2 < 2; ++nt2) {
            #pragma unroll
            for (int dt = 0; dt < 4; ++dt) {
                short8 vv = *(const short8*)(lds_v[p] + (dt * 16 + l15) * 64 +
                                             (((quad * 2 + nt2) ^ sw7) << 3));
                short4v vlo = __builtin_shufflevector(vv, vv, 0, 1, 2, 3);
                short4v vhi = __builtin_shufflevector(vv, vv, 4, 5, 6, 7);
                O0[dt] = __builtin_amdgcn_mfma_f32_16x16x16bf16_1k(vlo, pf0[2 * nt2],     O0[dt], 0, 0, 0);
                O0[dt] = __builtin_amdgcn_mfma_f32_16x16x16bf16_1k(vhi, pf0[2 * nt2 + 1], O0[dt], 0, 0, 0);
                O1[dt] = __builtin_amdgcn_mfma_f32_16x16x16bf16_1k(vlo, pf1[2 * nt2],     O1[dt], 0, 0, 0);
                O1[dt] = __builtin_amdgcn_mfma_f32_16x16x16bf16_1k(vhi, pf1[2 * nt2 + 1], O1[dt], 0, 0, 0);
            }
        }
        __builtin_amdgcn_s_setprio(0);

        __syncthreads();
    }
    WRITE_O(O0, l0v, qrow_c0);
    WRITE_O(O1, l1v, qrow_c1);
}

// ---------- launcher ----------
extern "C" void kernel_launch(void* const* d_in, const int* in_sizes, int n_in,
                              void* d_out, int out_size, void* d_ws, size_t ws_size,
                              hipStream_t stream) {
    (void)in_sizes; (void)n_in; (void)out_size; (void)ws_size;
    const float* x  = (const float*)d_in[0];
    const float* Wq = (const float*)d_in[1];
    const float* Wk = (const float*)d_in[2];
    const float* Wv = (const float*)d_in[3];
    const float* Wo = (const float*)d_in[4];
    const float* qw = (const float*)d_in[5];
    const float* kw = (const float*)d_in[6];
    float* out = (float*)d_out;

    char* ws = (char*)d_ws;
    size_t off = 0;
    auto alloc = [&](size_t bytes) {
        char* p = ws + off;
        off += (bytes + 255) & ~(size_t)255;
        return p;
    };
    u16* xb     = (u16*)alloc((size_t)8388608 * 2);        // x bf16       16 MB
    u16* wqkv_t = (u16*)alloc((size_t)3072 * 2048 * 2);    // [n][k]       12 MB
    u16* wo_t   = (u16*)alloc((size_t)2048 * 2048 * 2);    //               8 MB
    u16* q_r    = (u16*)alloc((size_t)2 * 32 * 2048 * 64 * 2);  // 16 MB
    u16* k_r    = (u16*)alloc((size_t)2 * 8 * 2048 * 64 * 2);   //  4 MB (chunk-swizzled)
    u16* v_r    = (u16*)alloc((size_t)2 * 8 * 64 * 2048 * 2);   //  4 MB (d-major, P64+XOR swz)
    float2v* rtab = (float2v*)alloc((size_t)2048 * 32 * 8);     // 512 KB
    u16* attnb  = xb;   // reuse: xb dead after gemm_qkv

    hipLaunchKernelGGL(prep, dim3(13568), dim3(256), 0, stream,
                       (const float4v*)x, Wq, Wk, Wv, Wo,
                       (ushort4v*)xb, wqkv_t, wo_t, rtab);
    hipLaunchKernelGGL(gemm_qkv, dim3(16, 12), dim3(512), 0, stream,
                       xb, wqkv_t, qw, kw, rtab, q_r, k_r, v_r);
    hipLaunchKernelGGL(attn_fwd, dim3(64, 16), dim3(256), 0, stream, q_r, k_r, v_r, attnb);
    hipLaunchKernelGGL(gemm_bt, dim3(32, 16), dim3(256), 0, stream,
                       attnb, wo_t, out, 4096, 2048, 2048);
}